// Round 6
// baseline (444.549 us; speedup 1.0000x reference)
//
#include <hip/hip_runtime.h>
#include <hip/hip_bf16.h>

#define N_NODES 50000
#define N_EDGES 800000
#define FIN 256
#define EMB 128
#define NGRAPH 256
#define TOT_E (N_EDGES + N_NODES)

typedef __bf16 bf16;
typedef __attribute__((ext_vector_type(8))) __bf16 bf16x8;
typedef __attribute__((ext_vector_type(2))) __bf16 bf16x2;
typedef __attribute__((ext_vector_type(4))) float f32x4;

// ---------------- transpose + cast: W[rows][cols] f32 -> WT[cols][rows] bf16 ----------------
__global__ void transpose_kernel(const float* __restrict__ src, bf16* __restrict__ dst,
                                 int rows, int cols) {
    int t = blockIdx.x * 256 + threadIdx.x;
    if (t >= rows * cols) return;
    int c = t / rows, r = t - c * rows;   // dst linear index t = c*rows + r
    dst[t] = (bf16)src[r * cols + c];
}

// ---------------- CSR build, round-6: bucket-range, write-localized ----------------
// Round-5 scatter was write-amplification-bound: 850k random 4B stores cost 64B
// HBM lines each (WRITE_SIZE 57.4MB for 3.4MB payload; non-coherent XCD L2s never
// gather the lines). Bucket-range blocks localize all writes to a contiguous
// region; e_dst re-reads (49 x 3.4MB) are per-XCD-L2-resident.

// Block b owns nodes [b*1024, b*1024+1024): LDS histogram over all e_dst
// (self-loop = init 1), then fused in-LDS exclusive scan.
__global__ __launch_bounds__(1024)
void histscan_kernel(const int* __restrict__ e_dst, int* __restrict__ offsets,
                     int* __restrict__ blocksums) {
    __shared__ int hist[1024];
    int t = threadIdx.x;
    int base = blockIdx.x * 1024;
    int idx = base + t;
    hist[t] = (idx < N_NODES) ? 1 : 0;    // the self-loop edge
    __syncthreads();
    const int4* dst4 = (const int4*)e_dst;
    const int NQ = N_EDGES / 4;           // 200000, exact
    int lo = base, hi = base + 1024;
    for (int i = t; i < NQ; i += 1024) {
        int4 d4 = dst4[i];
        if (d4.x >= lo && d4.x < hi) atomicAdd(&hist[d4.x - lo], 1);
        if (d4.y >= lo && d4.y < hi) atomicAdd(&hist[d4.y - lo], 1);
        if (d4.z >= lo && d4.z < hi) atomicAdd(&hist[d4.z - lo], 1);
        if (d4.w >= lo && d4.w < hi) atomicAdd(&hist[d4.w - lo], 1);
    }
    __syncthreads();
    int v = hist[t];
    for (int d = 1; d < 1024; d <<= 1) {  // Hillis-Steele inclusive scan
        int u = (t >= d) ? hist[t - d] : 0;
        __syncthreads();
        hist[t] += u;
        __syncthreads();
    }
    if (idx < N_NODES) offsets[idx] = hist[t] - v;   // exclusive within chunk
    if (t == 1023) blocksums[blockIdx.x] = hist[1023];
}

// Stage 2: add chunk-prefix (64-lane masked reduce of 49 chunk totals).
__global__ __launch_bounds__(1024)
void scan_fix_kernel(int* __restrict__ offsets, const int* __restrict__ blocksums,
                     int nblk) {
    __shared__ int sprefix;
    int t = threadIdx.x, b = blockIdx.x;
    if (t < 64) {
        int v = (t < b && t < nblk) ? blocksums[t] : 0;
#pragma unroll
        for (int mk = 32; mk >= 1; mk >>= 1) v += __shfl_xor(v, mk);
        if (t == 0) sprefix = v;
    }
    __syncthreads();
    int idx = b * 1024 + t;
    if (idx < N_NODES) offsets[idx] += sprefix;
    if (idx == 0) offsets[N_NODES] = TOT_E;
}

// Block b scatters only edges with dst in its range; LDS cursors; writes land in
// the block's contiguous CSR region (L2-gathered before writeback).
__global__ __launch_bounds__(1024)
void scatter_kernel2(const int* __restrict__ e_src, const int* __restrict__ e_dst,
                     const int* __restrict__ offsets, int* __restrict__ sorted_src) {
    __shared__ int cur[1024];
    int t = threadIdx.x;
    int base = blockIdx.x * 1024;
    int idx = base + t;
    cur[t] = (idx < N_NODES) ? offsets[idx] : 0;
    __syncthreads();
    if (idx < N_NODES) {                  // insert the self-loop
        int p = atomicAdd(&cur[t], 1);
        sorted_src[p] = idx;
    }
    const int4* dst4 = (const int4*)e_dst;
    const int4* src4 = (const int4*)e_src;
    const int NQ = N_EDGES / 4;
    int lo = base, hi = base + 1024;
    for (int i = t; i < NQ; i += 1024) {
        int4 d4 = dst4[i];
        bool ix = (d4.x >= lo && d4.x < hi), iy = (d4.y >= lo && d4.y < hi);
        bool iz = (d4.z >= lo && d4.z < hi), iw = (d4.w >= lo && d4.w < hi);
        if (ix | iy | iz | iw) {          // ~8% of lanes: fetch src quad lazily
            int4 s4 = src4[i];
            if (ix) { int p = atomicAdd(&cur[d4.x - lo], 1); sorted_src[p] = s4.x; }
            if (iy) { int p = atomicAdd(&cur[d4.y - lo], 1); sorted_src[p] = s4.y; }
            if (iz) { int p = atomicAdd(&cur[d4.z - lo], 1); sorted_src[p] = s4.z; }
            if (iw) { int p = atomicAdd(&cur[d4.w - lo], 1); sorted_src[p] = s4.w; }
        }
    }
}

// ---------------- GEMM: C[M][128] = A[M][K] * W[K][128], W given transposed+bf16 WT[128][K]
template<int K, typename AT>
__global__ __launch_bounds__(256)
void gemm_kernel(const AT* __restrict__ A, const bf16* __restrict__ WT,
                 bf16* __restrict__ C, int M) {
    __shared__ __align__(16) bf16 As[64][32];
    __shared__ __align__(16) bf16 Bs[128][32];
    int tid = threadIdx.x;
    int wave = tid >> 6, lane = tid & 63;
    int m0 = blockIdx.x * 64;

    f32x4 acc[8];
#pragma unroll
    for (int i = 0; i < 8; ++i) acc[i] = (f32x4){0.f, 0.f, 0.f, 0.f};

    int arow = tid >> 2, aseg = tid & 3;

    for (int k0 = 0; k0 < K; k0 += 32) {
        {
            int gr = m0 + arow;
            if constexpr (sizeof(AT) == 4) {
                bf16x8 av = (bf16x8){0, 0, 0, 0, 0, 0, 0, 0};
                if (gr < M) {
                    const float* ap = (const float*)A + (size_t)gr * K + k0 + aseg * 8;
                    float4 f0 = *(const float4*)(ap);
                    float4 f1 = *(const float4*)(ap + 4);
                    av = (bf16x8){(bf16)f0.x, (bf16)f0.y, (bf16)f0.z, (bf16)f0.w,
                                  (bf16)f1.x, (bf16)f1.y, (bf16)f1.z, (bf16)f1.w};
                }
                *(bf16x8*)(&As[arow][aseg * 8]) = av;
            } else {
                uint4 av = make_uint4(0u, 0u, 0u, 0u);
                if (gr < M) av = *(const uint4*)((const bf16*)A + (size_t)gr * K + k0 + aseg * 8);
                *(uint4*)(&As[arow][aseg * 8]) = av;
            }
        }
#pragma unroll
        for (int it = 0; it < 2; ++it) {
            int c = tid + it * 256;
            int col = c >> 2, seg = c & 3;
            *(uint4*)(&Bs[col][seg * 8]) =
                *(const uint4*)(WT + (size_t)col * K + k0 + seg * 8);
        }
        __syncthreads();
        bf16x8 af = *(const bf16x8*)(&As[wave * 16 + (lane & 15)][(lane >> 4) * 8]);
#pragma unroll
        for (int n = 0; n < 8; ++n) {
            bf16x8 bfr = *(const bf16x8*)(&Bs[n * 16 + (lane & 15)][(lane >> 4) * 8]);
            acc[n] = __builtin_amdgcn_mfma_f32_16x16x32_bf16(af, bfr, acc[n], 0, 0, 0);
        }
        __syncthreads();
    }
    int rbase = m0 + wave * 16 + ((lane >> 4) << 2);
    int cbase = lane & 15;
#pragma unroll
    for (int n = 0; n < 8; ++n) {
#pragma unroll
        for (int r = 0; r < 4; ++r) {
            int row = rbase + r;
            if (row < M) C[(size_t)row * 128 + n * 16 + cbase] = (bf16)acc[n][r];
        }
    }
}

// ---------------- per-node attention scores ----------------
__global__ __launch_bounds__(256)
void scores_kernel(const bf16* __restrict__ h, const float* __restrict__ a_src,
                   const float* __restrict__ a_dst, float* __restrict__ s_src,
                   float* __restrict__ s_dst) {
    int wave = threadIdx.x >> 6, lane = threadIdx.x & 63;
    int node = blockIdx.x * 4 + wave;
    if (node >= N_NODES) return;
    bf16x2 hv = *(const bf16x2*)(h + (size_t)node * 128 + 2 * lane);
    float2 as = *(const float2*)(a_src + 2 * lane);
    float2 ad = *(const float2*)(a_dst + 2 * lane);
    float h0 = (float)hv[0], h1 = (float)hv[1];
    float ps = h0 * as.x + h1 * as.y;
    float pd = h0 * ad.x + h1 * ad.y;
#pragma unroll
    for (int m = 32; m >= 1; m >>= 1) {
        ps += __shfl_xor(ps, m);
        pd += __shfl_xor(pd, m);
    }
    if (lane == 0) { s_src[node] = ps; s_dst[node] = pd; }
}

// ---------------- per-node softmax-aggregate (16-lane groups, 4 nodes/wave) ----------------
template<typename OUT_T>
__global__ __launch_bounds__(256)
void agg_kernel(const int* __restrict__ offsets, const int* __restrict__ sorted_src,
                const float* __restrict__ s_src, const float* __restrict__ s_dst,
                const bf16* __restrict__ h, const float* __restrict__ bias,
                OUT_T* __restrict__ out) {
    int tid = threadIdx.x;
    int wave = tid >> 6, lane = tid & 63;
    int gl = lane & 15;                      // lane within 16-lane group
    int gbase = lane & 48;                   // group's base lane in wave (grp*16)
    int d = blockIdx.x * 16 + wave * 4 + (lane >> 4);
    if (d >= N_NODES) return;
    int r0 = offsets[d];
    int deg = offsets[d + 1] - r0;
    float sd = s_dst[d];

    // pass 1: slots 0..31 in registers; e-values + group max
    int sv0 = 0, sv1 = 0;
    float ev0 = -INFINITY, ev1 = -INFINITY;
    if (gl < deg) {
        sv0 = sorted_src[r0 + gl];
        float e = s_src[sv0] + sd;
        ev0 = (e > 0.f) ? e : 0.2f * e;
    }
    if (16 + gl < deg) {
        sv1 = sorted_src[r0 + 16 + gl];
        float e = s_src[sv1] + sd;
        ev1 = (e > 0.f) ? e : 0.2f * e;
    }
    float m = fmaxf(ev0, ev1);
    for (int i = 32 + gl; i < deg; i += 16) {          // rare tail (deg > 32)
        int s = sorted_src[r0 + i];
        float e = s_src[s] + sd;
        e = (e > 0.f) ? e : 0.2f * e;
        m = fmaxf(m, e);
    }
#pragma unroll
    for (int mk = 8; mk >= 1; mk >>= 1) m = fmaxf(m, __shfl_xor(m, mk));

    // pass 2: p = exp(e-m), group denominator
    float pv0 = (gl < deg) ? __expf(ev0 - m) : 0.f;
    float pv1 = (16 + gl < deg) ? __expf(ev1 - m) : 0.f;
    float den = pv0 + pv1;
    for (int i = 32 + gl; i < deg; i += 16) {          // rare tail
        int s = sorted_src[r0 + i];
        float e = s_src[s] + sd;
        e = (e > 0.f) ? e : 0.2f * e;
        den += __expf(e - m);
    }
#pragma unroll
    for (int mk = 8; mk >= 1; mk >>= 1) den += __shfl_xor(den, mk);

    // pass 3: weighted gather, lane owns 8 feats (16B bf16x8 loads)
    float acc[8];
#pragma unroll
    for (int k = 0; k < 8; ++k) acc[k] = 0.f;

    int jm = (deg < 32) ? deg : 32;
#pragma unroll 4
    for (int j = 0; j < jm; ++j) {
        int src_lane = gbase + (j & 15);
        int s = __shfl((j < 16) ? sv0 : sv1, src_lane);
        float p = __shfl((j < 16) ? pv0 : pv1, src_lane);
        bf16x8 hv = *(const bf16x8*)(h + (size_t)s * 128 + gl * 8);
#pragma unroll
        for (int k = 0; k < 8; ++k) acc[k] += p * (float)hv[k];
    }
    for (int i = 32; i < deg; ++i) {                   // rare tail, group-serial
        int s = sorted_src[r0 + i];
        float e = s_src[s] + sd;
        e = (e > 0.f) ? e : 0.2f * e;
        float p = __expf(e - m);
        bf16x8 hv = *(const bf16x8*)(h + (size_t)s * 128 + gl * 8);
#pragma unroll
        for (int k = 0; k < 8; ++k) acc[k] += p * (float)hv[k];
    }

    float inv = 1.f / den;
    float4 bv0 = *(const float4*)(bias + gl * 8);
    float4 bv1 = *(const float4*)(bias + gl * 8 + 4);
    float o[8] = {acc[0] * inv + bv0.x, acc[1] * inv + bv0.y,
                  acc[2] * inv + bv0.z, acc[3] * inv + bv0.w,
                  acc[4] * inv + bv1.x, acc[5] * inv + bv1.y,
                  acc[6] * inv + bv1.z, acc[7] * inv + bv1.w};
    if constexpr (sizeof(OUT_T) == 2) {
        bf16x8 ov;
#pragma unroll
        for (int k = 0; k < 8; ++k) ov[k] = (bf16)o[k];
        *(bf16x8*)((bf16*)out + (size_t)d * 128 + gl * 8) = ov;
    } else {
        float* op = (float*)out + (size_t)d * 128 + gl * 8;
        *(float4*)op       = (float4){o[0], o[1], o[2], o[3]};
        *(float4*)(op + 4) = (float4){o[4], o[5], o[6], o[7]};
    }
}

// ---------------- per-graph mean/max pooling (batch_idx sorted) ----------------
__global__ __launch_bounds__(256)
void pool_kernel(const float* __restrict__ out2, const int* __restrict__ batch_idx,
                 float* __restrict__ mean, float* __restrict__ mx) {
    int g = blockIdx.x;
    int j = threadIdx.x & 127;
    int grp = threadIdx.x >> 7;
    int lo = 0, hi = N_NODES;
    while (lo < hi) { int mid = (lo + hi) >> 1; if (batch_idx[mid] < g) lo = mid + 1; else hi = mid; }
    int start = lo;
    hi = N_NODES;
    while (lo < hi) { int mid = (lo + hi) >> 1; if (batch_idx[mid] < g + 1) lo = mid + 1; else hi = mid; }
    int end = lo;

    float s = 0.f, mmax = -INFINITY;
    for (int r = start + grp; r < end; r += 2) {
        float v = out2[(size_t)r * 128 + j];
        s += v;
        mmax = fmaxf(mmax, v);
    }
    __shared__ float ls[2][128], lm[2][128];
    ls[grp][j] = s; lm[grp][j] = mmax;
    __syncthreads();
    if (grp == 0) {
        int cnt = end - start;
        float sum = ls[0][j] + ls[1][j];
        float mv = fmaxf(lm[0][j], lm[1][j]);
        mean[g * 128 + j] = sum / fmaxf((float)cnt, 1.f);
        mx[g * 128 + j] = (cnt > 0) ? mv : 0.f;
    }
}

// ---------------- head ----------------
__global__ __launch_bounds__(128)
void head_kernel(const float* __restrict__ mean, const float* __restrict__ mx,
                 const float* __restrict__ gfeat, const float* __restrict__ Wg,
                 const float* __restrict__ bg, const float* __restrict__ Wo,
                 const float* __restrict__ bo, float* __restrict__ out) {
    int g = blockIdx.x;
    int j = threadIdx.x;   // 0..127
    float gft = bg[j];
#pragma unroll
    for (int k = 0; k < 32; ++k)
        gft += gfeat[g * 32 + k] * Wg[k * 128 + j];
    float mj = mean[g * 128 + j], xj = mx[g * 128 + j];
    float p0 = mj * Wo[j * 2 + 0] + xj * Wo[(128 + j) * 2 + 0] + gft * Wo[(256 + j) * 2 + 0];
    float p1 = mj * Wo[j * 2 + 1] + xj * Wo[(128 + j) * 2 + 1] + gft * Wo[(256 + j) * 2 + 1];
#pragma unroll
    for (int m = 32; m >= 1; m >>= 1) { p0 += __shfl_xor(p0, m); p1 += __shfl_xor(p1, m); }
    __shared__ float l0s[2], l1s[2];
    int wv = j >> 6;
    if ((j & 63) == 0) { l0s[wv] = p0; l1s[wv] = p1; }
    __syncthreads();
    if (j == 0) {
        float l0 = l0s[0] + l0s[1] + bo[0];   // per-logit cross-wave combine
        float l1 = l1s[0] + l1s[1] + bo[1];
        float mm = fmaxf(l0, l1);
        float lse = mm + logf(__expf(l0 - mm) + __expf(l1 - mm));
        out[g * 2 + 0] = l0 - lse;
        out[g * 2 + 1] = l1 - lse;
    }
}

extern "C" void kernel_launch(void* const* d_in, const int* in_sizes, int n_in,
                              void* d_out, int out_size, void* d_ws, size_t ws_size,
                              hipStream_t stream) {
    const float* x     = (const float*)d_in[0];
    const int*   edges = (const int*)d_in[1];     // [2][E] flat
    const int*   batch = (const int*)d_in[2];
    const float* gfeat = (const float*)d_in[3];
    const float* W1    = (const float*)d_in[4];
    const float* a1s   = (const float*)d_in[5];
    const float* a1d   = (const float*)d_in[6];
    const float* b1    = (const float*)d_in[7];
    const float* W2    = (const float*)d_in[8];
    const float* a2s   = (const float*)d_in[9];
    const float* a2d   = (const float*)d_in[10];
    const float* b2    = (const float*)d_in[11];
    const float* Wg    = (const float*)d_in[12];
    const float* bg    = (const float*)d_in[13];
    const float* Wo    = (const float*)d_in[14];
    const float* bo    = (const float*)d_in[15];

    char* ws = (char*)d_ws;
    bf16*  WT1     = (bf16*)(ws + 0);          //  65536 B
    bf16*  WT2     = (bf16*)(ws + 65536);      //  32768 B
    float* s_src   = (float*)(ws + 98304);     // 200704 B
    float* s_dst   = (float*)(ws + 299008);    // 200704 B
    int*   blocksums = (int*)(ws + 699712);    // 196 B
    int*   offsets = (int*)(ws + 700416);      // 200704 B (N+1 ints)
    int*   sorted  = (int*)(ws + 1101824);     // 3400704 B
    bf16*  h       = (bf16*)(ws + 4502528);    // 12.8 MB (h1, then reused for h2)
    bf16*  out1    = (bf16*)(ws + 17302528);   // 12.8 MB
    float* out2    = (float*)(ws + 30102528);  // 25.6 MB
    float* pmean   = (float*)(ws + 55702528);  // 131072 B
    float* pmax    = (float*)(ws + 55833600);  // 131072 B

    const int* e_src = edges;
    const int* e_dst = edges + N_EDGES;

    // --- W transposes + f32->bf16 cast (tiny) ---
    transpose_kernel<<<(FIN * EMB + 255) / 256, 256, 0, stream>>>(W1, WT1, FIN, EMB);
    transpose_kernel<<<(EMB * EMB + 255) / 256, 256, 0, stream>>>(W2, WT2, EMB, EMB);

    // --- CSR by dst (shared by both layers): bucket-range build, no global atomics ---
    int nblk = (N_NODES + 1023) / 1024;   // 49
    histscan_kernel<<<nblk, 1024, 0, stream>>>(e_dst, offsets, blocksums);
    scan_fix_kernel<<<nblk, 1024, 0, stream>>>(offsets, blocksums, nblk);
    scatter_kernel2<<<nblk, 1024, 0, stream>>>(e_src, e_dst, offsets, sorted);

    int gemm_blocks = (N_NODES + 63) / 64;
    int score_blocks = (N_NODES + 3) / 4;
    int agg_blocks = (N_NODES + 15) / 16;   // 16 nodes/block (4 waves x 4 groups)

    // --- layer 1 ---
    gemm_kernel<FIN, float><<<gemm_blocks, 256, 0, stream>>>(x, WT1, h, N_NODES);
    scores_kernel<<<score_blocks, 256, 0, stream>>>(h, a1s, a1d, s_src, s_dst);
    agg_kernel<bf16><<<agg_blocks, 256, 0, stream>>>(offsets, sorted, s_src, s_dst, h, b1, out1);

    // --- layer 2 ---
    gemm_kernel<EMB, bf16><<<gemm_blocks, 256, 0, stream>>>(out1, WT2, h, N_NODES);
    scores_kernel<<<score_blocks, 256, 0, stream>>>(h, a2s, a2d, s_src, s_dst);
    agg_kernel<float><<<agg_blocks, 256, 0, stream>>>(offsets, sorted, s_src, s_dst, h, b2, out2);

    // --- pooling + head ---
    pool_kernel<<<NGRAPH, 256, 0, stream>>>(out2, batch, pmean, pmax);
    head_kernel<<<NGRAPH, 128, 0, stream>>>(pmean, pmax, gfeat, Wg, bg, Wo, bo, (float*)d_out);
}

// Round 7
// 443.931 us; speedup vs baseline: 1.0014x; 1.0014x over previous
//
#include <hip/hip_runtime.h>
#include <hip/hip_bf16.h>

#define N_NODES 50000
#define N_EDGES 800000
#define FIN 256
#define EMB 128
#define NGRAPH 256
#define TOT_E (N_EDGES + N_NODES)

typedef __bf16 bf16;
typedef __attribute__((ext_vector_type(8))) __bf16 bf16x8;
typedef __attribute__((ext_vector_type(2))) __bf16 bf16x2;
typedef __attribute__((ext_vector_type(4))) float f32x4;

// ---------------- transpose + cast: W[rows][cols] f32 -> WT[cols][rows] bf16 ----------------
__global__ void transpose_kernel(const float* __restrict__ src, bf16* __restrict__ dst,
                                 int rows, int cols) {
    int t = blockIdx.x * 256 + threadIdx.x;
    if (t >= rows * cols) return;
    int c = t / rows, r = t - c * rows;   // dst linear index t = c*rows + r
    dst[t] = (bf16)src[r * cols + c];
}

// ---------------- CSR build, round-6: bucket-range, write-localized ----------------
// Round-5 scatter was write-amplification-bound: 850k random 4B stores cost 64B
// HBM lines each (WRITE_SIZE 57.4MB for 3.4MB payload; non-coherent XCD L2s never
// gather the lines). Bucket-range blocks localize all writes to a contiguous
// region; e_dst re-reads (49 x 3.4MB) are per-XCD-L2-resident.

// Block b owns nodes [b*1024, b*1024+1024): LDS histogram over all e_dst
// (self-loop = init 1), then fused in-LDS exclusive scan.
__global__ __launch_bounds__(1024)
void histscan_kernel(const int* __restrict__ e_dst, int* __restrict__ offsets,
                     int* __restrict__ blocksums) {
    __shared__ int hist[1024];
    int t = threadIdx.x;
    int base = blockIdx.x * 1024;
    int idx = base + t;
    hist[t] = (idx < N_NODES) ? 1 : 0;    // the self-loop edge
    __syncthreads();
    const int4* dst4 = (const int4*)e_dst;
    const int NQ = N_EDGES / 4;           // 200000, exact
    int lo = base, hi = base + 1024;
    for (int i = t; i < NQ; i += 1024) {
        int4 d4 = dst4[i];
        if (d4.x >= lo && d4.x < hi) atomicAdd(&hist[d4.x - lo], 1);
        if (d4.y >= lo && d4.y < hi) atomicAdd(&hist[d4.y - lo], 1);
        if (d4.z >= lo && d4.z < hi) atomicAdd(&hist[d4.z - lo], 1);
        if (d4.w >= lo && d4.w < hi) atomicAdd(&hist[d4.w - lo], 1);
    }
    __syncthreads();
    int v = hist[t];
    for (int d = 1; d < 1024; d <<= 1) {  // Hillis-Steele inclusive scan
        int u = (t >= d) ? hist[t - d] : 0;
        __syncthreads();
        hist[t] += u;
        __syncthreads();
    }
    if (idx < N_NODES) offsets[idx] = hist[t] - v;   // exclusive within chunk
    if (t == 1023) blocksums[blockIdx.x] = hist[1023];
}

// Stage 2: add chunk-prefix (64-lane masked reduce of 49 chunk totals).
__global__ __launch_bounds__(1024)
void scan_fix_kernel(int* __restrict__ offsets, const int* __restrict__ blocksums,
                     int nblk) {
    __shared__ int sprefix;
    int t = threadIdx.x, b = blockIdx.x;
    if (t < 64) {
        int v = (t < b && t < nblk) ? blocksums[t] : 0;
#pragma unroll
        for (int mk = 32; mk >= 1; mk >>= 1) v += __shfl_xor(v, mk);
        if (t == 0) sprefix = v;
    }
    __syncthreads();
    int idx = b * 1024 + t;
    if (idx < N_NODES) offsets[idx] += sprefix;
    if (idx == 0) offsets[N_NODES] = TOT_E;
}

// Block b scatters only edges with dst in its range; LDS cursors; writes land in
// the block's contiguous CSR region (L2-gathered before writeback).
__global__ __launch_bounds__(1024)
void scatter_kernel2(const int* __restrict__ e_src, const int* __restrict__ e_dst,
                     const int* __restrict__ offsets, int* __restrict__ sorted_src) {
    __shared__ int cur[1024];
    int t = threadIdx.x;
    int base = blockIdx.x * 1024;
    int idx = base + t;
    cur[t] = (idx < N_NODES) ? offsets[idx] : 0;
    __syncthreads();
    if (idx < N_NODES) {                  // insert the self-loop
        int p = atomicAdd(&cur[t], 1);
        sorted_src[p] = idx;
    }
    const int4* dst4 = (const int4*)e_dst;
    const int4* src4 = (const int4*)e_src;
    const int NQ = N_EDGES / 4;
    int lo = base, hi = base + 1024;
    for (int i = t; i < NQ; i += 1024) {
        int4 d4 = dst4[i];
        bool ix = (d4.x >= lo && d4.x < hi), iy = (d4.y >= lo && d4.y < hi);
        bool iz = (d4.z >= lo && d4.z < hi), iw = (d4.w >= lo && d4.w < hi);
        if (ix | iy | iz | iw) {          // ~8% of lanes: fetch src quad lazily
            int4 s4 = src4[i];
            if (ix) { int p = atomicAdd(&cur[d4.x - lo], 1); sorted_src[p] = s4.x; }
            if (iy) { int p = atomicAdd(&cur[d4.y - lo], 1); sorted_src[p] = s4.y; }
            if (iz) { int p = atomicAdd(&cur[d4.z - lo], 1); sorted_src[p] = s4.z; }
            if (iw) { int p = atomicAdd(&cur[d4.w - lo], 1); sorted_src[p] = s4.w; }
        }
    }
}

// ---------------- GEMM: C[M][128] = A[M][K] * W[K][128], W given transposed+bf16 WT[128][K]
template<int K, typename AT>
__global__ __launch_bounds__(256)
void gemm_kernel(const AT* __restrict__ A, const bf16* __restrict__ WT,
                 bf16* __restrict__ C, int M) {
    __shared__ __align__(16) bf16 As[64][32];
    __shared__ __align__(16) bf16 Bs[128][32];
    int tid = threadIdx.x;
    int wave = tid >> 6, lane = tid & 63;
    int m0 = blockIdx.x * 64;

    f32x4 acc[8];
#pragma unroll
    for (int i = 0; i < 8; ++i) acc[i] = (f32x4){0.f, 0.f, 0.f, 0.f};

    int arow = tid >> 2, aseg = tid & 3;

    for (int k0 = 0; k0 < K; k0 += 32) {
        {
            int gr = m0 + arow;
            if constexpr (sizeof(AT) == 4) {
                bf16x8 av = (bf16x8){0, 0, 0, 0, 0, 0, 0, 0};
                if (gr < M) {
                    const float* ap = (const float*)A + (size_t)gr * K + k0 + aseg * 8;
                    float4 f0 = *(const float4*)(ap);
                    float4 f1 = *(const float4*)(ap + 4);
                    av = (bf16x8){(bf16)f0.x, (bf16)f0.y, (bf16)f0.z, (bf16)f0.w,
                                  (bf16)f1.x, (bf16)f1.y, (bf16)f1.z, (bf16)f1.w};
                }
                *(bf16x8*)(&As[arow][aseg * 8]) = av;
            } else {
                uint4 av = make_uint4(0u, 0u, 0u, 0u);
                if (gr < M) av = *(const uint4*)((const bf16*)A + (size_t)gr * K + k0 + aseg * 8);
                *(uint4*)(&As[arow][aseg * 8]) = av;
            }
        }
#pragma unroll
        for (int it = 0; it < 2; ++it) {
            int c = tid + it * 256;
            int col = c >> 2, seg = c & 3;
            *(uint4*)(&Bs[col][seg * 8]) =
                *(const uint4*)(WT + (size_t)col * K + k0 + seg * 8);
        }
        __syncthreads();
        bf16x8 af = *(const bf16x8*)(&As[wave * 16 + (lane & 15)][(lane >> 4) * 8]);
#pragma unroll
        for (int n = 0; n < 8; ++n) {
            bf16x8 bfr = *(const bf16x8*)(&Bs[n * 16 + (lane & 15)][(lane >> 4) * 8]);
            acc[n] = __builtin_amdgcn_mfma_f32_16x16x32_bf16(af, bfr, acc[n], 0, 0, 0);
        }
        __syncthreads();
    }
    int rbase = m0 + wave * 16 + ((lane >> 4) << 2);
    int cbase = lane & 15;
#pragma unroll
    for (int n = 0; n < 8; ++n) {
#pragma unroll
        for (int r = 0; r < 4; ++r) {
            int row = rbase + r;
            if (row < M) C[(size_t)row * 128 + n * 16 + cbase] = (bf16)acc[n][r];
        }
    }
}

// ---------------- per-node attention scores ----------------
__global__ __launch_bounds__(256)
void scores_kernel(const bf16* __restrict__ h, const float* __restrict__ a_src,
                   const float* __restrict__ a_dst, float* __restrict__ s_src,
                   float* __restrict__ s_dst) {
    int wave = threadIdx.x >> 6, lane = threadIdx.x & 63;
    int node = blockIdx.x * 4 + wave;
    if (node >= N_NODES) return;
    bf16x2 hv = *(const bf16x2*)(h + (size_t)node * 128 + 2 * lane);
    float2 as = *(const float2*)(a_src + 2 * lane);
    float2 ad = *(const float2*)(a_dst + 2 * lane);
    float h0 = (float)hv[0], h1 = (float)hv[1];
    float ps = h0 * as.x + h1 * as.y;
    float pd = h0 * ad.x + h1 * ad.y;
#pragma unroll
    for (int m = 32; m >= 1; m >>= 1) {
        ps += __shfl_xor(ps, m);
        pd += __shfl_xor(pd, m);
    }
    if (lane == 0) { s_src[node] = ps; s_dst[node] = pd; }
}

// ---------------- per-node softmax-aggregate (16-lane groups, 4 nodes/wave) ----------------
template<typename OUT_T>
__global__ __launch_bounds__(256)
void agg_kernel(const int* __restrict__ offsets, const int* __restrict__ sorted_src,
                const float* __restrict__ s_src, const float* __restrict__ s_dst,
                const bf16* __restrict__ h, const float* __restrict__ bias,
                OUT_T* __restrict__ out) {
    int tid = threadIdx.x;
    int wave = tid >> 6, lane = tid & 63;
    int gl = lane & 15;                      // lane within 16-lane group
    int gbase = lane & 48;                   // group's base lane in wave (grp*16)
    int d = blockIdx.x * 16 + wave * 4 + (lane >> 4);
    if (d >= N_NODES) return;
    int r0 = offsets[d];
    int deg = offsets[d + 1] - r0;
    float sd = s_dst[d];

    // pass 1: slots 0..31 in registers; e-values + group max
    int sv0 = 0, sv1 = 0;
    float ev0 = -INFINITY, ev1 = -INFINITY;
    if (gl < deg) {
        sv0 = sorted_src[r0 + gl];
        float e = s_src[sv0] + sd;
        ev0 = (e > 0.f) ? e : 0.2f * e;
    }
    if (16 + gl < deg) {
        sv1 = sorted_src[r0 + 16 + gl];
        float e = s_src[sv1] + sd;
        ev1 = (e > 0.f) ? e : 0.2f * e;
    }
    float m = fmaxf(ev0, ev1);
    for (int i = 32 + gl; i < deg; i += 16) {          // rare tail (deg > 32)
        int s = sorted_src[r0 + i];
        float e = s_src[s] + sd;
        e = (e > 0.f) ? e : 0.2f * e;
        m = fmaxf(m, e);
    }
#pragma unroll
    for (int mk = 8; mk >= 1; mk >>= 1) m = fmaxf(m, __shfl_xor(m, mk));

    // pass 2: p = exp(e-m), group denominator
    float pv0 = (gl < deg) ? __expf(ev0 - m) : 0.f;
    float pv1 = (16 + gl < deg) ? __expf(ev1 - m) : 0.f;
    float den = pv0 + pv1;
    for (int i = 32 + gl; i < deg; i += 16) {          // rare tail
        int s = sorted_src[r0 + i];
        float e = s_src[s] + sd;
        e = (e > 0.f) ? e : 0.2f * e;
        den += __expf(e - m);
    }
#pragma unroll
    for (int mk = 8; mk >= 1; mk >>= 1) den += __shfl_xor(den, mk);

    // pass 3: weighted gather, lane owns 8 feats (16B bf16x8 loads)
    float acc[8];
#pragma unroll
    for (int k = 0; k < 8; ++k) acc[k] = 0.f;

    int jm = (deg < 32) ? deg : 32;
#pragma unroll 4
    for (int j = 0; j < jm; ++j) {
        int src_lane = gbase + (j & 15);
        int s = __shfl((j < 16) ? sv0 : sv1, src_lane);
        float p = __shfl((j < 16) ? pv0 : pv1, src_lane);
        bf16x8 hv = *(const bf16x8*)(h + (size_t)s * 128 + gl * 8);
#pragma unroll
        for (int k = 0; k < 8; ++k) acc[k] += p * (float)hv[k];
    }
    for (int i = 32; i < deg; ++i) {                   // rare tail, group-serial
        int s = sorted_src[r0 + i];
        float e = s_src[s] + sd;
        e = (e > 0.f) ? e : 0.2f * e;
        float p = __expf(e - m);
        bf16x8 hv = *(const bf16x8*)(h + (size_t)s * 128 + gl * 8);
#pragma unroll
        for (int k = 0; k < 8; ++k) acc[k] += p * (float)hv[k];
    }

    float inv = 1.f / den;
    float4 bv0 = *(const float4*)(bias + gl * 8);
    float4 bv1 = *(const float4*)(bias + gl * 8 + 4);
    float o[8] = {acc[0] * inv + bv0.x, acc[1] * inv + bv0.y,
                  acc[2] * inv + bv0.z, acc[3] * inv + bv0.w,
                  acc[4] * inv + bv1.x, acc[5] * inv + bv1.y,
                  acc[6] * inv + bv1.z, acc[7] * inv + bv1.w};
    if constexpr (sizeof(OUT_T) == 2) {
        bf16x8 ov;
#pragma unroll
        for (int k = 0; k < 8; ++k) ov[k] = (bf16)o[k];
        *(bf16x8*)((bf16*)out + (size_t)d * 128 + gl * 8) = ov;
    } else {
        float* op = (float*)out + (size_t)d * 128 + gl * 8;
        *(float4*)op       = (float4){o[0], o[1], o[2], o[3]};
        *(float4*)(op + 4) = (float4){o[4], o[5], o[6], o[7]};
    }
}

// ---------------- per-graph mean/max pooling (batch_idx sorted) ----------------
__global__ __launch_bounds__(256)
void pool_kernel(const float* __restrict__ out2, const int* __restrict__ batch_idx,
                 float* __restrict__ mean, float* __restrict__ mx) {
    int g = blockIdx.x;
    int j = threadIdx.x & 127;
    int grp = threadIdx.x >> 7;
    int lo = 0, hi = N_NODES;
    while (lo < hi) { int mid = (lo + hi) >> 1; if (batch_idx[mid] < g) lo = mid + 1; else hi = mid; }
    int start = lo;
    hi = N_NODES;
    while (lo < hi) { int mid = (lo + hi) >> 1; if (batch_idx[mid] < g + 1) lo = mid + 1; else hi = mid; }
    int end = lo;

    float s = 0.f, mmax = -INFINITY;
    for (int r = start + grp; r < end; r += 2) {
        float v = out2[(size_t)r * 128 + j];
        s += v;
        mmax = fmaxf(mmax, v);
    }
    __shared__ float ls[2][128], lm[2][128];
    ls[grp][j] = s; lm[grp][j] = mmax;
    __syncthreads();
    if (grp == 0) {
        int cnt = end - start;
        float sum = ls[0][j] + ls[1][j];
        float mv = fmaxf(lm[0][j], lm[1][j]);
        mean[g * 128 + j] = sum / fmaxf((float)cnt, 1.f);
        mx[g * 128 + j] = (cnt > 0) ? mv : 0.f;
    }
}

// ---------------- head ----------------
__global__ __launch_bounds__(128)
void head_kernel(const float* __restrict__ mean, const float* __restrict__ mx,
                 const float* __restrict__ gfeat, const float* __restrict__ Wg,
                 const float* __restrict__ bg, const float* __restrict__ Wo,
                 const float* __restrict__ bo, float* __restrict__ out) {
    int g = blockIdx.x;
    int j = threadIdx.x;   // 0..127
    float gft = bg[j];
#pragma unroll
    for (int k = 0; k < 32; ++k)
        gft += gfeat[g * 32 + k] * Wg[k * 128 + j];
    float mj = mean[g * 128 + j], xj = mx[g * 128 + j];
    float p0 = mj * Wo[j * 2 + 0] + xj * Wo[(128 + j) * 2 + 0] + gft * Wo[(256 + j) * 2 + 0];
    float p1 = mj * Wo[j * 2 + 1] + xj * Wo[(128 + j) * 2 + 1] + gft * Wo[(256 + j) * 2 + 1];
#pragma unroll
    for (int m = 32; m >= 1; m >>= 1) { p0 += __shfl_xor(p0, m); p1 += __shfl_xor(p1, m); }
    __shared__ float l0s[2], l1s[2];
    int wv = j >> 6;
    if ((j & 63) == 0) { l0s[wv] = p0; l1s[wv] = p1; }
    __syncthreads();
    if (j == 0) {
        float l0 = l0s[0] + l0s[1] + bo[0];   // per-logit cross-wave combine
        float l1 = l1s[0] + l1s[1] + bo[1];
        float mm = fmaxf(l0, l1);
        float lse = mm + logf(__expf(l0 - mm) + __expf(l1 - mm));
        out[g * 2 + 0] = l0 - lse;
        out[g * 2 + 1] = l1 - lse;
    }
}

extern "C" void kernel_launch(void* const* d_in, const int* in_sizes, int n_in,
                              void* d_out, int out_size, void* d_ws, size_t ws_size,
                              hipStream_t stream) {
    const float* x     = (const float*)d_in[0];
    const int*   edges = (const int*)d_in[1];     // [2][E] flat
    const int*   batch = (const int*)d_in[2];
    const float* gfeat = (const float*)d_in[3];
    const float* W1    = (const float*)d_in[4];
    const float* a1s   = (const float*)d_in[5];
    const float* a1d   = (const float*)d_in[6];
    const float* b1    = (const float*)d_in[7];
    const float* W2    = (const float*)d_in[8];
    const float* a2s   = (const float*)d_in[9];
    const float* a2d   = (const float*)d_in[10];
    const float* b2    = (const float*)d_in[11];
    const float* Wg    = (const float*)d_in[12];
    const float* bg    = (const float*)d_in[13];
    const float* Wo    = (const float*)d_in[14];
    const float* bo    = (const float*)d_in[15];

    char* ws = (char*)d_ws;
    bf16*  WT1     = (bf16*)(ws + 0);          //  65536 B
    bf16*  WT2     = (bf16*)(ws + 65536);      //  32768 B
    float* s_src   = (float*)(ws + 98304);     // 200704 B
    float* s_dst   = (float*)(ws + 299008);    // 200704 B
    int*   blocksums = (int*)(ws + 699712);    // 196 B
    int*   offsets = (int*)(ws + 700416);      // 200704 B (N+1 ints)
    int*   sorted  = (int*)(ws + 1101824);     // 3400704 B
    bf16*  h       = (bf16*)(ws + 4502528);    // 12.8 MB (h1, then reused for h2)
    bf16*  out1    = (bf16*)(ws + 17302528);   // 12.8 MB
    float* out2    = (float*)(ws + 30102528);  // 25.6 MB
    float* pmean   = (float*)(ws + 55702528);  // 131072 B
    float* pmax    = (float*)(ws + 55833600);  // 131072 B

    const int* e_src = edges;
    const int* e_dst = edges + N_EDGES;

    // --- W transposes + f32->bf16 cast (tiny) ---
    transpose_kernel<<<(FIN * EMB + 255) / 256, 256, 0, stream>>>(W1, WT1, FIN, EMB);
    transpose_kernel<<<(EMB * EMB + 255) / 256, 256, 0, stream>>>(W2, WT2, EMB, EMB);

    // --- CSR by dst (shared by both layers): bucket-range build, no global atomics ---
    int nblk = (N_NODES + 1023) / 1024;   // 49
    histscan_kernel<<<nblk, 1024, 0, stream>>>(e_dst, offsets, blocksums);
    scan_fix_kernel<<<nblk, 1024, 0, stream>>>(offsets, blocksums, nblk);
    scatter_kernel2<<<nblk, 1024, 0, stream>>>(e_src, e_dst, offsets, sorted);

    int gemm_blocks = (N_NODES + 63) / 64;
    int score_blocks = (N_NODES + 3) / 4;
    int agg_blocks = (N_NODES + 15) / 16;   // 16 nodes/block (4 waves x 4 groups)

    // --- layer 1 ---
    gemm_kernel<FIN, float><<<gemm_blocks, 256, 0, stream>>>(x, WT1, h, N_NODES);
    scores_kernel<<<score_blocks, 256, 0, stream>>>(h, a1s, a1d, s_src, s_dst);
    agg_kernel<bf16><<<agg_blocks, 256, 0, stream>>>(offsets, sorted, s_src, s_dst, h, b1, out1);

    // --- layer 2 ---
    gemm_kernel<EMB, bf16><<<gemm_blocks, 256, 0, stream>>>(out1, WT2, h, N_NODES);
    scores_kernel<<<score_blocks, 256, 0, stream>>>(h, a2s, a2d, s_src, s_dst);
    agg_kernel<float><<<agg_blocks, 256, 0, stream>>>(offsets, sorted, s_src, s_dst, h, b2, out2);

    // --- pooling + head ---
    pool_kernel<<<NGRAPH, 256, 0, stream>>>(out2, batch, pmean, pmax);
    head_kernel<<<NGRAPH, 128, 0, stream>>>(pmean, pmax, gfeat, Wg, bg, Wo, bo, (float*)d_out);
}

// Round 8
// 263.790 us; speedup vs baseline: 1.6852x; 1.6829x over previous
//
#include <hip/hip_runtime.h>
#include <hip/hip_bf16.h>

#define N_NODES 50000
#define N_EDGES 800000
#define FIN 256
#define EMB 128
#define NGRAPH 256
#define TOT_E (N_EDGES + N_NODES)
#define NCHUNK 32          // edge chunks per range in scatter3
#define NRANGE 49          // ceil(N_NODES/1024)

typedef __bf16 bf16;
typedef __attribute__((ext_vector_type(8))) __bf16 bf16x8;
typedef __attribute__((ext_vector_type(2))) __bf16 bf16x2;
typedef __attribute__((ext_vector_type(4))) float f32x4;

// ---------------- transpose + cast: W[rows][cols] f32 -> WT[cols][rows] bf16 ----------------
__global__ void transpose_kernel(const float* __restrict__ src, bf16* __restrict__ dst,
                                 int rows, int cols) {
    int t = blockIdx.x * 256 + threadIdx.x;
    if (t >= rows * cols) return;
    int c = t / rows, r = t - c * rows;
    dst[t] = (bf16)src[r * cols + c];
}

// ---------------- CSR build ----------------
// Round-8 structure: round-5's fast hist/scan (edge-parallel, high occupancy)
// + round-6's write-localized scatter, but parallelized: 49 ranges x 32 edge
// chunks, XCD-pinned (blockIdx%8 round-robin heuristic) so each node's CSR
// segment is written from one XCD's L2 only (keeps WRITE_SIZE ~4MB instead of
// 57MB line-amplified), with 1568 active blocks instead of 49 (round-7 was
// occupancy-starved at 8.9%: 200us).
__global__ void hist_kernel(const int* __restrict__ e_dst, int* __restrict__ counts) {
    int e = blockIdx.x * 256 + threadIdx.x;
    if (e >= TOT_E) return;
    int d = (e < N_EDGES) ? e_dst[e] : (e - N_EDGES);
    atomicAdd(&counts[d], 1);
}

__global__ __launch_bounds__(1024)
void scan_block_kernel(const int* __restrict__ counts, int* __restrict__ offsets,
                       int* __restrict__ blocksums) {
    __shared__ int lds[1024];
    int t = threadIdx.x;
    int idx = blockIdx.x * 1024 + t;
    int v = (idx < N_NODES) ? counts[idx] : 0;
    lds[t] = v;
    __syncthreads();
    for (int d = 1; d < 1024; d <<= 1) {
        int u = (t >= d) ? lds[t - d] : 0;
        __syncthreads();
        lds[t] += u;
        __syncthreads();
    }
    if (idx < N_NODES) offsets[idx] = lds[t] - v;     // exclusive within chunk
    if (t == 1023) blocksums[blockIdx.x] = lds[1023];
}

// Adds chunk prefix; also seeds cursor[] and the self-loop CSR entry (order
// within a neighbor list is permutation-invariant through segment softmax).
__global__ __launch_bounds__(1024)
void scan_fix_kernel(int* __restrict__ offsets, const int* __restrict__ blocksums,
                     int nblk, int* __restrict__ cursor, int* __restrict__ sorted_src) {
    __shared__ int sprefix;
    int t = threadIdx.x, b = blockIdx.x;
    if (t < 64) {
        int v = (t < b && t < nblk) ? blocksums[t] : 0;
#pragma unroll
        for (int mk = 32; mk >= 1; mk >>= 1) v += __shfl_xor(v, mk);
        if (t == 0) sprefix = v;
    }
    __syncthreads();
    int idx = b * 1024 + t;
    if (idx < N_NODES) {
        int off = offsets[idx] + sprefix;
        offsets[idx] = off;
        cursor[idx] = off + 1;       // slot 0 taken by the self-loop
        sorted_src[off] = idx;       // self-loop entry
    }
    if (idx == 0) offsets[N_NODES] = TOT_E;
}

// Block (xcd=bid&7, slot=bid>>3): chunk = slot/7 (chunk-major so co-resident
// blocks on an XCD stream the same e_dst chunk), ri = slot%7, range r = ri*8+xcd.
// Filters its edge chunk for dst in [r*1024, r*1024+1024); global-atomic cursor.
__global__ __launch_bounds__(1024)
void scatter_kernel3(const int* __restrict__ e_src, const int* __restrict__ e_dst,
                     int* __restrict__ cursor, int* __restrict__ sorted_src) {
    int bid = blockIdx.x;
    int x = bid & 7;
    int slot = bid >> 3;
    int chunk = slot / 7;
    int ri = slot - chunk * 7;
    int r = ri * 8 + x;
    if (r >= NRANGE) return;
    int lo = r * 1024, hi = lo + 1024;
    const int NQ = N_EDGES / 4;                      // 200000
    int q0 = (int)(((long long)chunk * NQ) / NCHUNK);
    int q1 = (int)(((long long)(chunk + 1) * NQ) / NCHUNK);
    const int4* dst4 = (const int4*)e_dst;
    const int4* src4 = (const int4*)e_src;
    for (int i = q0 + threadIdx.x; i < q1; i += 1024) {
        int4 d4 = dst4[i];
        bool ix = (d4.x >= lo && d4.x < hi), iy = (d4.y >= lo && d4.y < hi);
        bool iz = (d4.z >= lo && d4.z < hi), iw = (d4.w >= lo && d4.w < hi);
        if (ix | iy | iz | iw) {
            int4 s4 = src4[i];
            if (ix) sorted_src[atomicAdd(&cursor[d4.x], 1)] = s4.x;
            if (iy) sorted_src[atomicAdd(&cursor[d4.y], 1)] = s4.y;
            if (iz) sorted_src[atomicAdd(&cursor[d4.z], 1)] = s4.z;
            if (iw) sorted_src[atomicAdd(&cursor[d4.w], 1)] = s4.w;
        }
    }
}

// ---------------- GEMM: C[M][128] = A[M][K] * W[K][128], W given transposed+bf16 WT[128][K]
template<int K, typename AT>
__global__ __launch_bounds__(256)
void gemm_kernel(const AT* __restrict__ A, const bf16* __restrict__ WT,
                 bf16* __restrict__ C, int M) {
    __shared__ __align__(16) bf16 As[64][32];
    __shared__ __align__(16) bf16 Bs[128][32];
    int tid = threadIdx.x;
    int wave = tid >> 6, lane = tid & 63;
    int m0 = blockIdx.x * 64;

    f32x4 acc[8];
#pragma unroll
    for (int i = 0; i < 8; ++i) acc[i] = (f32x4){0.f, 0.f, 0.f, 0.f};

    int arow = tid >> 2, aseg = tid & 3;

    for (int k0 = 0; k0 < K; k0 += 32) {
        {
            int gr = m0 + arow;
            if constexpr (sizeof(AT) == 4) {
                bf16x8 av = (bf16x8){0, 0, 0, 0, 0, 0, 0, 0};
                if (gr < M) {
                    const float* ap = (const float*)A + (size_t)gr * K + k0 + aseg * 8;
                    float4 f0 = *(const float4*)(ap);
                    float4 f1 = *(const float4*)(ap + 4);
                    av = (bf16x8){(bf16)f0.x, (bf16)f0.y, (bf16)f0.z, (bf16)f0.w,
                                  (bf16)f1.x, (bf16)f1.y, (bf16)f1.z, (bf16)f1.w};
                }
                *(bf16x8*)(&As[arow][aseg * 8]) = av;
            } else {
                uint4 av = make_uint4(0u, 0u, 0u, 0u);
                if (gr < M) av = *(const uint4*)((const bf16*)A + (size_t)gr * K + k0 + aseg * 8);
                *(uint4*)(&As[arow][aseg * 8]) = av;
            }
        }
#pragma unroll
        for (int it = 0; it < 2; ++it) {
            int c = tid + it * 256;
            int col = c >> 2, seg = c & 3;
            *(uint4*)(&Bs[col][seg * 8]) =
                *(const uint4*)(WT + (size_t)col * K + k0 + seg * 8);
        }
        __syncthreads();
        bf16x8 af = *(const bf16x8*)(&As[wave * 16 + (lane & 15)][(lane >> 4) * 8]);
#pragma unroll
        for (int n = 0; n < 8; ++n) {
            bf16x8 bfr = *(const bf16x8*)(&Bs[n * 16 + (lane & 15)][(lane >> 4) * 8]);
            acc[n] = __builtin_amdgcn_mfma_f32_16x16x32_bf16(af, bfr, acc[n], 0, 0, 0);
        }
        __syncthreads();
    }
    int rbase = m0 + wave * 16 + ((lane >> 4) << 2);
    int cbase = lane & 15;
#pragma unroll
    for (int n = 0; n < 8; ++n) {
#pragma unroll
        for (int r = 0; r < 4; ++r) {
            int row = rbase + r;
            if (row < M) C[(size_t)row * 128 + n * 16 + cbase] = (bf16)acc[n][r];
        }
    }
}

// ---------------- per-node attention scores ----------------
__global__ __launch_bounds__(256)
void scores_kernel(const bf16* __restrict__ h, const float* __restrict__ a_src,
                   const float* __restrict__ a_dst, float* __restrict__ s_src,
                   float* __restrict__ s_dst) {
    int wave = threadIdx.x >> 6, lane = threadIdx.x & 63;
    int node = blockIdx.x * 4 + wave;
    if (node >= N_NODES) return;
    bf16x2 hv = *(const bf16x2*)(h + (size_t)node * 128 + 2 * lane);
    float2 as = *(const float2*)(a_src + 2 * lane);
    float2 ad = *(const float2*)(a_dst + 2 * lane);
    float h0 = (float)hv[0], h1 = (float)hv[1];
    float ps = h0 * as.x + h1 * as.y;
    float pd = h0 * ad.x + h1 * ad.y;
#pragma unroll
    for (int m = 32; m >= 1; m >>= 1) {
        ps += __shfl_xor(ps, m);
        pd += __shfl_xor(pd, m);
    }
    if (lane == 0) { s_src[node] = ps; s_dst[node] = pd; }
}

// ---------------- per-node softmax-aggregate (16-lane groups, 4 nodes/wave) ----------------
template<typename OUT_T>
__global__ __launch_bounds__(256)
void agg_kernel(const int* __restrict__ offsets, const int* __restrict__ sorted_src,
                const float* __restrict__ s_src, const float* __restrict__ s_dst,
                const bf16* __restrict__ h, const float* __restrict__ bias,
                OUT_T* __restrict__ out) {
    int tid = threadIdx.x;
    int wave = tid >> 6, lane = tid & 63;
    int gl = lane & 15;
    int gbase = lane & 48;
    int d = blockIdx.x * 16 + wave * 4 + (lane >> 4);
    if (d >= N_NODES) return;
    int r0 = offsets[d];
    int deg = offsets[d + 1] - r0;
    float sd = s_dst[d];

    int sv0 = 0, sv1 = 0;
    float ev0 = -INFINITY, ev1 = -INFINITY;
    if (gl < deg) {
        sv0 = sorted_src[r0 + gl];
        float e = s_src[sv0] + sd;
        ev0 = (e > 0.f) ? e : 0.2f * e;
    }
    if (16 + gl < deg) {
        sv1 = sorted_src[r0 + 16 + gl];
        float e = s_src[sv1] + sd;
        ev1 = (e > 0.f) ? e : 0.2f * e;
    }
    float m = fmaxf(ev0, ev1);
    for (int i = 32 + gl; i < deg; i += 16) {
        int s = sorted_src[r0 + i];
        float e = s_src[s] + sd;
        e = (e > 0.f) ? e : 0.2f * e;
        m = fmaxf(m, e);
    }
#pragma unroll
    for (int mk = 8; mk >= 1; mk >>= 1) m = fmaxf(m, __shfl_xor(m, mk));

    float pv0 = (gl < deg) ? __expf(ev0 - m) : 0.f;
    float pv1 = (16 + gl < deg) ? __expf(ev1 - m) : 0.f;
    float den = pv0 + pv1;
    for (int i = 32 + gl; i < deg; i += 16) {
        int s = sorted_src[r0 + i];
        float e = s_src[s] + sd;
        e = (e > 0.f) ? e : 0.2f * e;
        den += __expf(e - m);
    }
#pragma unroll
    for (int mk = 8; mk >= 1; mk >>= 1) den += __shfl_xor(den, mk);

    float acc[8];
#pragma unroll
    for (int k = 0; k < 8; ++k) acc[k] = 0.f;

    int jm = (deg < 32) ? deg : 32;
#pragma unroll 4
    for (int j = 0; j < jm; ++j) {
        int src_lane = gbase + (j & 15);
        int s = __shfl((j < 16) ? sv0 : sv1, src_lane);
        float p = __shfl((j < 16) ? pv0 : pv1, src_lane);
        bf16x8 hv = *(const bf16x8*)(h + (size_t)s * 128 + gl * 8);
#pragma unroll
        for (int k = 0; k < 8; ++k) acc[k] += p * (float)hv[k];
    }
    for (int i = 32; i < deg; ++i) {
        int s = sorted_src[r0 + i];
        float e = s_src[s] + sd;
        e = (e > 0.f) ? e : 0.2f * e;
        float p = __expf(e - m);
        bf16x8 hv = *(const bf16x8*)(h + (size_t)s * 128 + gl * 8);
#pragma unroll
        for (int k = 0; k < 8; ++k) acc[k] += p * (float)hv[k];
    }

    float inv = 1.f / den;
    float4 bv0 = *(const float4*)(bias + gl * 8);
    float4 bv1 = *(const float4*)(bias + gl * 8 + 4);
    float o[8] = {acc[0] * inv + bv0.x, acc[1] * inv + bv0.y,
                  acc[2] * inv + bv0.z, acc[3] * inv + bv0.w,
                  acc[4] * inv + bv1.x, acc[5] * inv + bv1.y,
                  acc[6] * inv + bv1.z, acc[7] * inv + bv1.w};
    if constexpr (sizeof(OUT_T) == 2) {
        bf16x8 ov;
#pragma unroll
        for (int k = 0; k < 8; ++k) ov[k] = (bf16)o[k];
        *(bf16x8*)((bf16*)out + (size_t)d * 128 + gl * 8) = ov;
    } else {
        float* op = (float*)out + (size_t)d * 128 + gl * 8;
        *(float4*)op       = (float4){o[0], o[1], o[2], o[3]};
        *(float4*)(op + 4) = (float4){o[4], o[5], o[6], o[7]};
    }
}

// ---------------- per-graph mean/max pooling (batch_idx sorted) ----------------
__global__ __launch_bounds__(256)
void pool_kernel(const float* __restrict__ out2, const int* __restrict__ batch_idx,
                 float* __restrict__ mean, float* __restrict__ mx) {
    int g = blockIdx.x;
    int j = threadIdx.x & 127;
    int grp = threadIdx.x >> 7;
    int lo = 0, hi = N_NODES;
    while (lo < hi) { int mid = (lo + hi) >> 1; if (batch_idx[mid] < g) lo = mid + 1; else hi = mid; }
    int start = lo;
    hi = N_NODES;
    while (lo < hi) { int mid = (lo + hi) >> 1; if (batch_idx[mid] < g + 1) lo = mid + 1; else hi = mid; }
    int end = lo;

    float s = 0.f, mmax = -INFINITY;
    for (int r = start + grp; r < end; r += 2) {
        float v = out2[(size_t)r * 128 + j];
        s += v;
        mmax = fmaxf(mmax, v);
    }
    __shared__ float ls[2][128], lm[2][128];
    ls[grp][j] = s; lm[grp][j] = mmax;
    __syncthreads();
    if (grp == 0) {
        int cnt = end - start;
        float sum = ls[0][j] + ls[1][j];
        float mv = fmaxf(lm[0][j], lm[1][j]);
        mean[g * 128 + j] = sum / fmaxf((float)cnt, 1.f);
        mx[g * 128 + j] = (cnt > 0) ? mv : 0.f;
    }
}

// ---------------- head ----------------
__global__ __launch_bounds__(128)
void head_kernel(const float* __restrict__ mean, const float* __restrict__ mx,
                 const float* __restrict__ gfeat, const float* __restrict__ Wg,
                 const float* __restrict__ bg, const float* __restrict__ Wo,
                 const float* __restrict__ bo, float* __restrict__ out) {
    int g = blockIdx.x;
    int j = threadIdx.x;
    float gft = bg[j];
#pragma unroll
    for (int k = 0; k < 32; ++k)
        gft += gfeat[g * 32 + k] * Wg[k * 128 + j];
    float mj = mean[g * 128 + j], xj = mx[g * 128 + j];
    float p0 = mj * Wo[j * 2 + 0] + xj * Wo[(128 + j) * 2 + 0] + gft * Wo[(256 + j) * 2 + 0];
    float p1 = mj * Wo[j * 2 + 1] + xj * Wo[(128 + j) * 2 + 1] + gft * Wo[(256 + j) * 2 + 1];
#pragma unroll
    for (int m = 32; m >= 1; m >>= 1) { p0 += __shfl_xor(p0, m); p1 += __shfl_xor(p1, m); }
    __shared__ float l0s[2], l1s[2];
    int wv = j >> 6;
    if ((j & 63) == 0) { l0s[wv] = p0; l1s[wv] = p1; }
    __syncthreads();
    if (j == 0) {
        float l0 = l0s[0] + l0s[1] + bo[0];
        float l1 = l1s[0] + l1s[1] + bo[1];
        float mm = fmaxf(l0, l1);
        float lse = mm + logf(__expf(l0 - mm) + __expf(l1 - mm));
        out[g * 2 + 0] = l0 - lse;
        out[g * 2 + 1] = l1 - lse;
    }
}

extern "C" void kernel_launch(void* const* d_in, const int* in_sizes, int n_in,
                              void* d_out, int out_size, void* d_ws, size_t ws_size,
                              hipStream_t stream) {
    const float* x     = (const float*)d_in[0];
    const int*   edges = (const int*)d_in[1];
    const int*   batch = (const int*)d_in[2];
    const float* gfeat = (const float*)d_in[3];
    const float* W1    = (const float*)d_in[4];
    const float* a1s   = (const float*)d_in[5];
    const float* a1d   = (const float*)d_in[6];
    const float* b1    = (const float*)d_in[7];
    const float* W2    = (const float*)d_in[8];
    const float* a2s   = (const float*)d_in[9];
    const float* a2d   = (const float*)d_in[10];
    const float* b2    = (const float*)d_in[11];
    const float* Wg    = (const float*)d_in[12];
    const float* bg    = (const float*)d_in[13];
    const float* Wo    = (const float*)d_in[14];
    const float* bo    = (const float*)d_in[15];

    char* ws = (char*)d_ws;
    bf16*  WT1       = (bf16*)(ws + 0);          //  65536 B
    bf16*  WT2       = (bf16*)(ws + 65536);      //  32768 B
    float* s_src     = (float*)(ws + 98304);     // 200704 B
    float* s_dst     = (float*)(ws + 299008);    // 200704 B
    int*   counts    = (int*)(ws + 499712);      // 200000 B
    int*   blocksums = (int*)(ws + 699712);      // 196 B
    int*   offsets   = (int*)(ws + 700416);      // 200704 B (N+1 ints)
    int*   cursor    = (int*)(ws + 901120);      // 200704 B
    int*   sorted    = (int*)(ws + 1101824);     // 3400704 B
    bf16*  h         = (bf16*)(ws + 4502528);    // 12.8 MB
    bf16*  out1      = (bf16*)(ws + 17302528);   // 12.8 MB
    float* out2      = (float*)(ws + 30102528);  // 25.6 MB
    float* pmean     = (float*)(ws + 55702528);  // 131072 B
    float* pmax      = (float*)(ws + 55833600);  // 131072 B

    const int* e_src = edges;
    const int* e_dst = edges + N_EDGES;

    // --- W transposes + f32->bf16 cast (tiny) ---
    transpose_kernel<<<(FIN * EMB + 255) / 256, 256, 0, stream>>>(W1, WT1, FIN, EMB);
    transpose_kernel<<<(EMB * EMB + 255) / 256, 256, 0, stream>>>(W2, WT2, EMB, EMB);

    // --- CSR by dst: fast edge-parallel hist/scan + XCD-local chunked scatter ---
    hipMemsetAsync(counts, 0, N_NODES * sizeof(int), stream);
    int eb = (TOT_E + 255) / 256;
    hist_kernel<<<eb, 256, 0, stream>>>(e_dst, counts);
    int nblk = (N_NODES + 1023) / 1024;   // 49
    scan_block_kernel<<<nblk, 1024, 0, stream>>>(counts, offsets, blocksums);
    scan_fix_kernel<<<nblk, 1024, 0, stream>>>(offsets, blocksums, nblk, cursor, sorted);
    scatter_kernel3<<<8 * NCHUNK * 7, 1024, 0, stream>>>(e_src, e_dst, cursor, sorted);

    int gemm_blocks = (N_NODES + 63) / 64;
    int score_blocks = (N_NODES + 3) / 4;
    int agg_blocks = (N_NODES + 15) / 16;

    // --- layer 1 ---
    gemm_kernel<FIN, float><<<gemm_blocks, 256, 0, stream>>>(x, WT1, h, N_NODES);
    scores_kernel<<<score_blocks, 256, 0, stream>>>(h, a1s, a1d, s_src, s_dst);
    agg_kernel<bf16><<<agg_blocks, 256, 0, stream>>>(offsets, sorted, s_src, s_dst, h, b1, out1);

    // --- layer 2 ---
    gemm_kernel<EMB, bf16><<<gemm_blocks, 256, 0, stream>>>(out1, WT2, h, N_NODES);
    scores_kernel<<<score_blocks, 256, 0, stream>>>(h, a2s, a2d, s_src, s_dst);
    agg_kernel<float><<<agg_blocks, 256, 0, stream>>>(offsets, sorted, s_src, s_dst, h, b2, out2);

    // --- pooling + head ---
    pool_kernel<<<NGRAPH, 256, 0, stream>>>(out2, batch, pmean, pmax);
    head_kernel<<<NGRAPH, 128, 0, stream>>>(pmean, pmax, gfeat, Wg, bg, Wo, bo, (float*)d_out);
}